// Round 4
// baseline (11774.509 us; speedup 1.0000x reference)
//
#include <hip/hip_runtime.h>
#include <hip/hip_bf16.h>
#include <hip/hip_cooperative_groups.h>
#include <type_traits>

namespace cg = cooperative_groups;

#define HDIM 3072
#define TSTEPS 64

typedef __hip_bfloat16 bf16;

__device__ __forceinline__ float blo(unsigned u) { return __uint_as_float(u << 16); }
__device__ __forceinline__ float bhi(unsigned u) { return __uint_as_float(u & 0xffff0000u); }
__device__ __forceinline__ float sigm(float x) { return 1.f / (1.f + __expf(-x)); }
__device__ __forceinline__ float tanh_(float x) {
    float e = __expf(2.f * x);
    return 1.f - 2.f / (e + 1.f);
}

// ---------------- init: zero h buffers + out partials ----------------
__global__ void init_k(bf16* h1buf, bf16* h2buf, float* out_part) {
    int i = blockIdx.x * blockDim.x + threadIdx.x;  // 64*256 = 16384
    if (i < 2 * HDIM) { h1buf[i] = __float2bfloat16(0.f); h2buf[i] = __float2bfloat16(0.f); }
    out_part[i] = 0.f;  // exactly 16384 = 64*256
}

// ---------------- fp32 -> bf16 weight conversion ----------------
__global__ void cvt_k(const float* __restrict__ src, bf16* __restrict__ dst, int n) {
    int stride = gridDim.x * blockDim.x * 4;
    for (int i = (blockIdx.x * blockDim.x + threadIdx.x) * 4; i + 3 < n; i += stride) {
        float4 v = *reinterpret_cast<const float4*>(src + i);
        bf16 o[4] = { __float2bfloat16(v.x), __float2bfloat16(v.y),
                      __float2bfloat16(v.z), __float2bfloat16(v.w) };
        *reinterpret_cast<uint2*>(dst + i) = *reinterpret_cast<const uint2*>(o);
    }
}

// ---------------- conv 3x3 p1 + relu + maxpool 3x3 s2 p1, all T frames ----------------
// grid 3072 blocks (k = c*1024 + oy*32 + ox), 64 threads (t). Writes featT[k][t] fp32.
__global__ void conv_pool_k(const float* __restrict__ in, const float* __restrict__ cw,
                            const float* __restrict__ cb, float* __restrict__ featT) {
    int k = blockIdx.x;
    int t = threadIdx.x;
    int c = k >> 10, oy = (k >> 5) & 31, ox = k & 31;
    float w[9];
#pragma unroll
    for (int q = 0; q < 9; ++q) w[q] = cw[c * 9 + q];
    float b = cb[c];
    float m = 0.f;  // relu >= 0 so 0 is a safe identity for the pool max
    for (int ph = 0; ph < 3; ++ph) {
        int py = 2 * oy - 1 + ph;
        if (py < 0 || py > 63) continue;
        for (int pw = 0; pw < 3; ++pw) {
            int px = 2 * ox - 1 + pw;
            if (px < 0 || px > 63) continue;
            float s = b;
#pragma unroll
            for (int kh = 0; kh < 3; ++kh) {
                int iy = py + kh - 1;
                if (iy < 0 || iy > 63) continue;
#pragma unroll
                for (int kw = 0; kw < 3; ++kw) {
                    int ix = px + kw - 1;
                    if (ix < 0 || ix > 63) continue;
                    s = fmaf(in[((iy << 6) + ix) * TSTEPS + t], w[kh * 3 + kw], s);
                }
            }
            s = fmaxf(s, 0.f);
            m = fmaxf(m, s);
        }
    }
    featT[k * 64 + t] = m;
}

// ---------------- batched linear over T: yT[n][t] = sum_k W[n][k]*xT[k][t] + b1[n](+b2[n]) ----
// t lives in lanes (coalesced), weights are wave-uniform loads.
// block 256 = 4 waves, 8 rows per wave. grid = N/32.
__global__ void linear_k(const float* __restrict__ xT, const float* __restrict__ W,
                         const float* __restrict__ b1, const float* __restrict__ b2,
                         float* __restrict__ yT, int N, int K) {
    int lane = threadIdx.x & 63;
    int wid = __builtin_amdgcn_readfirstlane((int)(blockIdx.x * (blockDim.x >> 6) + (threadIdx.x >> 6)));
    int n0 = wid * 8;
    if (n0 >= N) return;
    const float* Wr = W + (size_t)n0 * K;
    float acc[8];
#pragma unroll
    for (int j = 0; j < 8; ++j) acc[j] = 0.f;
    for (int k = 0; k < K; k += 2) {
        float x0 = xT[k * 64 + lane];
        float x1 = xT[k * 64 + 64 + lane];
#pragma unroll
        for (int j = 0; j < 8; ++j) {
            float2 wv = *reinterpret_cast<const float2*>(Wr + (size_t)j * K + k);
            acc[j] = fmaf(wv.x, x0, fmaf(wv.y, x1, acc[j]));
        }
    }
#pragma unroll
    for (int j = 0; j < 8; ++j) {
        float bb = b1[n0 + j] + (b2 ? b2[n0 + j] : 0.f);
        yT[(size_t)(n0 + j) * 64 + lane] = acc[j] + bb;
    }
}

// ---------------- weight-fragment loaders (8 consecutive elements -> fp32[8]) ----------------
__device__ __forceinline__ void load8(const bf16* p, float* f) {
    uint4 a = *reinterpret_cast<const uint4*>(p);
    f[0] = blo(a.x); f[1] = bhi(a.x);
    f[2] = blo(a.y); f[3] = bhi(a.y);
    f[4] = blo(a.z); f[5] = bhi(a.z);
    f[6] = blo(a.w); f[7] = bhi(a.w);
}
__device__ __forceinline__ void load8(const float* p, float* f) {
    float4 a = *reinterpret_cast<const float4*>(p);
    float4 b = *reinterpret_cast<const float4*>(p + 4);
    f[0] = a.x; f[1] = a.y; f[2] = a.z; f[3] = a.w;
    f[4] = b.x; f[5] = b.y; f[6] = b.z; f[7] = b.w;
}

// ---------------- persistent cooperative RNN kernel ----------------
// 256 blocks x 1024 threads (16 waves). Block owns 12 gate-groups j (j0..j0+11).
// Phase p: computes h1[p] (layer0) and h2[p-1] (layer1, one step behind) -> 1 grid sync/phase.
// Per block per phase: 144 dot products of length 3072 (48 w_hh0 vs h1[p-1],
// 48 w_ih1 vs h1[p-1], 48 w_hh1 vs h2[p-2]). 16 waves * 9 dots each.
// Dot d = wave + 16*i: i<6 -> operand h1 (d<96), i>=6 -> operand h2 (d>=96).
template <bool WBF16>
__global__ void __launch_bounds__(1024, 4)
rnn_k(const void* w_hh0v, const void* w_ih1v, const void* w_hh1v,
      const float* __restrict__ b_ih1, const float* __restrict__ b_hh1,
      const float* __restrict__ out_w, const float* __restrict__ G0T,
      bf16* h1buf, bf16* h2buf, float* out_part) {
    using WT = typename std::conditional<WBF16, bf16, float>::type;
    const WT* w_hh0 = (const WT*)w_hh0v;
    const WT* w_ih1 = (const WT*)w_ih1v;
    const WT* w_hh1 = (const WT*)w_hh1v;

    cg::grid_group gg = cg::this_grid();
    const int blk = blockIdx.x;        // 0..255
    const int tid = threadIdx.x;       // 0..1023
    const int wave = tid >> 6;         // 0..15
    const int lane = tid & 63;
    const int j0 = blk * 12;

    __shared__ float gates[144];
    __shared__ float c1s[12], c2s[12];
    if (tid < 12) { c1s[tid] = 0.f; c2s[tid] = 0.f; }
    __syncthreads();

    const WT* wp[9];
#pragma unroll
    for (int i = 0; i < 9; ++i) {
        int d = wave + 16 * i;
        const WT* base;
        int r;
        if (d < 48)       { base = w_hh0; r = d; }
        else if (d < 96)  { base = w_ih1; r = d - 48; }
        else              { base = w_hh1; r = d - 96; }
        int g = r / 12, jo = r % 12;
        wp[i] = base + (size_t)(g * HDIM + j0 + jo) * HDIM + lane * 8;
    }

    for (int p = 0; p <= TSTEPS; ++p) {
        const bf16* h1p = h1buf + ((p + 1) & 1) * HDIM + lane * 8;  // h1[p-1]: slot (p-1)&1
        const bf16* h2p = h2buf + (p & 1) * HDIM + lane * 8;        // h2[p-2]: slot (p-2)&1
        float acc[9];
#pragma unroll
        for (int i = 0; i < 9; ++i) acc[i] = 0.f;
#pragma unroll
        for (int it = 0; it < 6; ++it) {
            float h1f[8], h2f[8];
            load8(h1p + it * 512, h1f);
            load8(h2p + it * 512, h2f);
#pragma unroll
            for (int i = 0; i < 9; ++i) {
                float w8[8];
                load8(wp[i] + it * 512, w8);
                const float* hf = (i < 6) ? h1f : h2f;
                acc[i] = fmaf(w8[0], hf[0], acc[i]);
                acc[i] = fmaf(w8[1], hf[1], acc[i]);
                acc[i] = fmaf(w8[2], hf[2], acc[i]);
                acc[i] = fmaf(w8[3], hf[3], acc[i]);
                acc[i] = fmaf(w8[4], hf[4], acc[i]);
                acc[i] = fmaf(w8[5], hf[5], acc[i]);
                acc[i] = fmaf(w8[6], hf[6], acc[i]);
                acc[i] = fmaf(w8[7], hf[7], acc[i]);
            }
        }
        // wave reduce + stash to LDS
#pragma unroll
        for (int i = 0; i < 9; ++i) {
            float v = acc[i];
            v += __shfl_xor(v, 32);
            v += __shfl_xor(v, 16);
            v += __shfl_xor(v, 8);
            v += __shfl_xor(v, 4);
            v += __shfl_xor(v, 2);
            v += __shfl_xor(v, 1);
            if (lane == 0) gates[wave + 16 * i] = v;
        }
        __syncthreads();
        // layer0 gates -> h1[p]
        if (p < TSTEPS && tid < 12) {
            int jo = tid, j = j0 + jo;
            float gi = G0T[(size_t)(0 * HDIM + j) * 64 + p] + gates[jo];
            float gf = G0T[(size_t)(1 * HDIM + j) * 64 + p] + gates[12 + jo];
            float gz = G0T[(size_t)(2 * HDIM + j) * 64 + p] + gates[24 + jo];
            float go = G0T[(size_t)(3 * HDIM + j) * 64 + p] + gates[36 + jo];
            float ii = sigm(gi), ff = sigm(gf), zz = tanh_(gz), oo = sigm(go);
            float c = ff * c1s[jo] + ii * zz;
            c1s[jo] = c;
            h1buf[(p & 1) * HDIM + j] = __float2bfloat16(oo * tanh_(c));
        }
        // layer1 gates (time t = p-1) -> h2[p-1], out[p-1]
        if (p >= 1 && tid >= 64 && tid < 76) {
            int jo = tid - 64, j = j0 + jo;
            float gi = gates[48 + jo]      + gates[96 + jo]      + b_ih1[0 * HDIM + j] + b_hh1[0 * HDIM + j];
            float gf = gates[48 + 12 + jo] + gates[96 + 12 + jo] + b_ih1[1 * HDIM + j] + b_hh1[1 * HDIM + j];
            float gz = gates[48 + 24 + jo] + gates[96 + 24 + jo] + b_ih1[2 * HDIM + j] + b_hh1[2 * HDIM + j];
            float go = gates[48 + 36 + jo] + gates[96 + 36 + jo] + b_ih1[3 * HDIM + j] + b_hh1[3 * HDIM + j];
            float ii = sigm(gi), ff = sigm(gf), zz = tanh_(gz), oo = sigm(go);
            float c = ff * c2s[jo] + ii * zz;
            c2s[jo] = c;
            float h = oo * tanh_(c);
            h2buf[((p + 1) & 1) * HDIM + j] = __float2bfloat16(h);  // slot (p-1)&1
            atomicAdd(&out_part[(p - 1) * 256 + blk], h * out_w[j]);
        }
        gg.sync();
    }
}

// ---------------- final: out[t] = sum_b out_part[t][b] + out_b ----------------
__global__ void final_k(const float* __restrict__ out_part, const float* __restrict__ out_b,
                        float* __restrict__ out) {
    int t = blockIdx.x;
    float v = out_part[t * 256 + threadIdx.x];
    v += __shfl_xor(v, 32);
    v += __shfl_xor(v, 16);
    v += __shfl_xor(v, 8);
    v += __shfl_xor(v, 4);
    v += __shfl_xor(v, 2);
    v += __shfl_xor(v, 1);
    __shared__ float sm[4];
    if ((threadIdx.x & 63) == 0) sm[threadIdx.x >> 6] = v;
    __syncthreads();
    if (threadIdx.x == 0)
        out[t] = sm[0] + sm[1] + sm[2] + sm[3] + out_b[0];
}

extern "C" void kernel_launch(void* const* d_in, const int* in_sizes, int n_in,
                              void* d_out, int out_size, void* d_ws, size_t ws_size,
                              hipStream_t stream) {
    const float* inp    = (const float*)d_in[0];
    const float* conv_w = (const float*)d_in[1];
    const float* conv_b = (const float*)d_in[2];
    const float* inp_w  = (const float*)d_in[3];
    const float* inp_b  = (const float*)d_in[4];
    const float* w_ih0  = (const float*)d_in[5];
    const float* w_hh0  = (const float*)d_in[6];
    const float* b_ih0  = (const float*)d_in[7];
    const float* b_hh0  = (const float*)d_in[8];
    const float* w_ih1  = (const float*)d_in[9];
    const float* w_hh1  = (const float*)d_in[10];
    const float* b_ih1  = (const float*)d_in[11];
    const float* b_hh1  = (const float*)d_in[12];
    const float* out_w  = (const float*)d_in[13];
    const float* out_b  = (const float*)d_in[14];

    char* ws = (char*)d_ws;
    float* featT    = (float*)(ws);                 // [3072][64] f32   786432 B
    float* XT       = (float*)(ws + 786432);        // [3072][64] f32   786432 B
    float* G0T      = (float*)(ws + 1572864);       // [12288][64] f32  3145728 B
    bf16*  h1buf    = (bf16*) (ws + 4718592);       // [2][3072] bf16   12288 B
    bf16*  h2buf    = (bf16*) (ws + 4730880);       // [2][3072] bf16   12288 B
    float* out_part = (float*)(ws + 4743168);       // [64][256] f32    65536 B
    bf16*  wb0      = (bf16*) (ws + 4808704);       // [12288][3072] bf16
    bf16*  wb1      = (bf16*) (ws + 4808704 + 75497472ull);
    bf16*  wb2      = (bf16*) (ws + 4808704 + 150994944ull);
    const size_t WS_NEED = 4808704ull + 3ull * 75497472ull;  // ~221 MiB
    float* out      = (float*)d_out;

    const int NW = 4 * HDIM * HDIM;  // 37748736 elements per recurrent matrix
    bool use_bf16 = (ws_size >= WS_NEED);

    init_k<<<dim3(64), dim3(256), 0, stream>>>(h1buf, h2buf, out_part);
    conv_pool_k<<<dim3(3072), dim3(64), 0, stream>>>(inp, conv_w, conv_b, featT);
    linear_k<<<dim3(96), dim3(256), 0, stream>>>(featT, inp_w, inp_b, nullptr, XT, 3072, 3072);
    linear_k<<<dim3(384), dim3(256), 0, stream>>>(XT, w_ih0, b_ih0, b_hh0, G0T, 12288, 3072);

    if (use_bf16) {
        cvt_k<<<dim3(2048), dim3(256), 0, stream>>>(w_hh0, wb0, NW);
        cvt_k<<<dim3(2048), dim3(256), 0, stream>>>(w_ih1, wb1, NW);
        cvt_k<<<dim3(2048), dim3(256), 0, stream>>>(w_hh1, wb2, NW);
        void* p0 = (void*)wb0; void* p1 = (void*)wb1; void* p2 = (void*)wb2;
        void* args[] = { &p0, &p1, &p2, (void*)&b_ih1, (void*)&b_hh1,
                         (void*)&out_w, (void*)&G0T, (void*)&h1buf, (void*)&h2buf, (void*)&out_part };
        hipLaunchCooperativeKernel((void*)rnn_k<true>, dim3(256), dim3(1024), args, 0, stream);
    } else {
        void* p0 = (void*)w_hh0; void* p1 = (void*)w_ih1; void* p2 = (void*)w_hh1;
        void* args[] = { &p0, &p1, &p2, (void*)&b_ih1, (void*)&b_hh1,
                         (void*)&out_w, (void*)&G0T, (void*)&h1buf, (void*)&h2buf, (void*)&out_part };
        hipLaunchCooperativeKernel((void*)rnn_k<false>, dim3(256), dim3(1024), args, 0, stream);
    }

    final_k<<<dim3(64), dim3(256), 0, stream>>>(out_part, out_b, out);
}